// Round 8
// baseline (1931.624 us; speedup 1.0000x reference)
//
#include <hip/hip_runtime.h>
#include <math.h>

#define BB 4
#define NP 8192
#define CF 64
#define MQ 2048
#define KS 32

// ---- workspace layout (float indices) ----
#define WS_G      0u         // g: [B][N][64] = W1_f·f_n + W1_dp·p_n (2097152 floats)
#define WS_NIDX   2097152u   // nidx: [B][M][K] int (262144)
#define WS_IDXI   2359296u   // idx int copy: [B][M] (8192)
#define WS_ST1    2367488u   // stats1 slices: [64][2][64] (8192)
#define WS_ST2    2375680u   // stats2 slices: [64][2][128] (16384)
#define WS_MAXY2  2392448u   // maxy2: [B*M][128] (1048576)

typedef float v2f __attribute__((ext_vector_type(2)));

// ------------------------------------------------------------------
// FPS v12 (fps body frozen; ~1620us steady): 256 thr / 32 pts.
// Shadow blocks 4..515 compute g[b][n][o] = W1_f·f_n + W1_dp·p_n
// (conv1's point-only part) on idle CUs under FPS's shadow.
// r8 fix: wlds padded [64][69] (stride 68 was 8-way bank conflict,
// 33K conflicts -> fps +13us interference).
// Dispatch chain collapsed 8 -> 5: ballq+p1 fused (p1 is light now),
// fin1 inlined into p2, fin2 inlined into p3 (1-block kernels cost
// more in launch gap than execution).
// ------------------------------------------------------------------
#define FPS_T 256
#define FPS_NK 16    // v2f pairs per thread: 32 points/thread

template <int CTRL>
__device__ __forceinline__ unsigned long long dpp_max_step(unsigned long long k) {
  int lo = (int)(unsigned)k;
  int hi = (int)(unsigned)(k >> 32);
  int slo = __builtin_amdgcn_update_dpp(0, lo, CTRL, 0xF, 0xF, true);
  int shi = __builtin_amdgcn_update_dpp(0, hi, CTRL, 0xF, 0xF, true);
  unsigned long long s =
      ((unsigned long long)(unsigned)shi << 32) | (unsigned long long)(unsigned)slo;
  return s > k ? s : k;
}

__global__ __launch_bounds__(256, 1) void fps_fused_kernel(
    const float* __restrict__ p, float* __restrict__ out, int* __restrict__ idx_i,
    const float* __restrict__ f, float* __restrict__ gout,
    const float* __restrict__ w1) {
#pragma clang fp contract(off)
  __shared__ __align__(16) char smem[NP * 16 + MQ * 4 + 2 * 4 * 8];
  int bx = blockIdx.x;
  int t = threadIdx.x;

  if (bx >= 4) {
    // ---- g block: tb in 0..511; b = tb>>7, n0 = (tb&127)*64 ----
    float (*tile)[65] = (float (*)[65])smem;                  // [64][65] f tile
    float (*wlds)[69] = (float (*)[69])(smem + 16640);        // [64][69] w1 rows (padded)
    float* plds = (float*)(smem + 16640 + 17664);             // [192] p coords
    int tb = bx - 4;
    int b = tb >> 7;
    int n0 = (tb & 127) * 64;
    int cc = t >> 6;   // 0..3
    int nn = t & 63;
    #pragma unroll
    for (int r = 0; r < 16; ++r) {
      int c = cc * 16 + r;
      tile[c][nn] = f[((size_t)b * 64 + c) * NP + n0 + nn];
    }
    for (int i = t; i < 64 * 67; i += 256) {
      wlds[i / 67][i % 67] = w1[i];
    }
    if (t < 192) plds[t] = p[((size_t)b * NP + n0) * 3 + t];
    __syncthreads();
    int wv = t >> 6, lane = t & 63;
    float wreg[67];
    #pragma unroll
    for (int c = 0; c < 67; ++c) wreg[c] = wlds[lane][c];
    for (int q = 0; q < 16; ++q) {
      int pt = wv * 16 + q;
      float acc = wreg[0] * plds[pt * 3 + 0];
      acc += wreg[1] * plds[pt * 3 + 1];
      acc += wreg[2] * plds[pt * 3 + 2];
      #pragma unroll
      for (int c = 0; c < 64; ++c) acc += wreg[3 + c] * tile[c][pt];
      gout[((size_t)b * NP + n0 + pt) * 64 + lane] = acc;
    }
    return;
  }

  // ---------------- FPS body (blocks 0..3, frozen) ----------------
  float4* sp4 = (float4*)smem;                                    // [NP]
  int* win = (int*)(smem + NP * 16);                              // [MQ]
  unsigned long long* wkey = (unsigned long long*)(smem + NP * 16 + MQ * 4); // [2][4]

  int b = bx;
  const float* pb = p + (size_t)b * NP * 3;
  float* out_newp = out;                               // [B][M][3]
  float* out_idxf = out + BB*MQ*3 + (size_t)BB*128*MQ; // [B][M] as float

  v2f px2[FPS_NK], py2[FPS_NK], pz2[FPS_NK];
  float dmn0[FPS_NK], dmn1[FPS_NK];          // even-slot / odd-slot dmin
  #pragma unroll
  for (int k = 0; k < FPS_NK; ++k) {
    int i0 = (2*k) * FPS_T + t;
    int i1 = i0 + FPS_T;
    float x0 = pb[i0*3+0], y0 = pb[i0*3+1], z0 = pb[i0*3+2];
    float x1 = pb[i1*3+0], y1 = pb[i1*3+1], z1 = pb[i1*3+2];
    px2[k] = (v2f){x0, x1}; py2[k] = (v2f){y0, y1}; pz2[k] = (v2f){z0, z1};
    sp4[i0] = make_float4(x0, y0, z0, 0.0f);
    sp4[i1] = make_float4(x1, y1, z1, 0.0f);
    dmn0[k] = INFINITY; dmn1[k] = INFINITY;
  }
  if (t == 0) win[0] = 0;
  __syncthreads();
  float lx = sp4[0].x, ly = sp4[0].y, lz = sp4[0].z;
  unsigned nt = ~(unsigned)t;

  for (int j = 1; j < MQ; ++j) {
#pragma clang fp contract(off)
    v2f l2x = (v2f){lx, lx}, l2y = (v2f){ly, ly}, l2z = (v2f){lz, lz};
    // dual strict-> argmax chains: chain0 = even slots (.x), chain1 = odd (.y)
    float bv0 = -1.0f, bv1 = -1.0f;
    unsigned bk0 = 0u, bk1 = 0u;
    #pragma unroll
    for (int k = 0; k < FPS_NK; ++k) {
      v2f dx = px2[k] - l2x;
      v2f dy = py2[k] - l2y;
      v2f dz = pz2[k] - l2z;
      v2f dd = ((dx*dx) + (dy*dy)) + (dz*dz);
      float m0 = fminf(dmn0[k], dd.x);  dmn0[k] = m0;
      float m1 = fminf(dmn1[k], dd.y);  dmn1[k] = m1;
      bool g0 = m0 > bv0;                 // strict > keeps earliest k
      bv0 = g0 ? m0 : bv0;
      bk0 = g0 ? (unsigned)k : bk0;
      bool g1 = m1 > bv1;
      bv1 = g1 ? m1 : bv1;
      bk1 = g1 ? (unsigned)k : bk1;
    }
    // ~((2*bk0)*256 + t) = nt - (bk0<<9); ~((2*bk1+1)*256 + t) = nt - (bk1<<9) - 256
    unsigned bn0 = nt - (bk0 << 9);
    unsigned bn1 = nt - (bk1 << 9) - 256u;
    unsigned long long k0 =
        ((unsigned long long)__float_as_uint(bv0) << 32) | (unsigned long long)bn0;
    unsigned long long k1 =
        ((unsigned long long)__float_as_uint(bv1) << 32) | (unsigned long long)bn1;
    unsigned long long key = k0 > k1 ? k0 : k1;   // ties: larger ~idx = smaller idx
    // DPP wave-max: result lands in lane 63
    key = dpp_max_step<0x111>(key);  // row_shr:1
    key = dpp_max_step<0x112>(key);  // row_shr:2
    key = dpp_max_step<0x114>(key);  // row_shr:4
    key = dpp_max_step<0x118>(key);  // row_shr:8
    key = dpp_max_step<0x142>(key);  // row_bcast15
    key = dpp_max_step<0x143>(key);  // row_bcast31
    if ((t & 63) == 63) wkey[(j & 1) * 4 + (t >> 6)] = key;   // 4 parallel slot writes
    __syncthreads();                 // single barrier per iteration
    const ulonglong2* wk2 = (const ulonglong2*)(&wkey[(j & 1) * 4]);
    ulonglong2 ka = wk2[0];          // broadcast ds_read_b128
    ulonglong2 kb = wk2[1];
    unsigned long long m0 = ka.x > ka.y ? ka.x : ka.y;
    unsigned long long m1 = kb.x > kb.y ? kb.x : kb.y;
    unsigned long long kw = m0 > m1 ? m0 : m1;
    int wi = (int)(~(unsigned)kw);
    float4 c = sp4[wi];              // one ds_read_b128, same-addr broadcast
    lx = c.x; ly = c.y; lz = c.z;
    if (t == 0) win[j] = wi;
  }

  __syncthreads();
  // bulk coalesced epilogue: idx (float + int) and new_p from LDS
  #pragma unroll
  for (int k = 0; k < MQ / FPS_T; ++k) {
    int j = k * FPS_T + t;
    int wi = win[j];
    out_idxf[b*MQ + j] = (float)wi;
    idx_i[b*MQ + j] = wi;
    float4 c = sp4[wi];
    float* np_ = &out_newp[(size_t)(b*MQ + j) * 3];
    np_[0] = c.x; np_[1] = c.y; np_[2] = c.z;
  }
}

// ------------------------------------------------------------------
// BP1 v2: fused ball query + conv1-stats. One wave per query; light
// LDS (~2.5KB, r4's 36KB-xbuf occupancy cliff is gone). Ballquery
// math bit-identical (rn ops, R2=f32(0.1*0.1), pad first-hit/0);
// scan software-pipelined: next chunk's 3 loads issue before the
// current ballot/branch (same values, same chunk order; OOB prefetch
// clamped to a safe in-bounds address, values unused).
// Then: nidx -> global (for p2) and conv1 stats via g-gather
// (a = g[n] - hq), indices read from LDS (same loads/ops as before).
// ------------------------------------------------------------------
__global__ __launch_bounds__(256) void bp1_kernel(
    const float* __restrict__ p, const float* __restrict__ newp,
    const float* __restrict__ g, const float* __restrict__ w1,
    int* __restrict__ nidx, float* __restrict__ stats1) {
  __shared__ int nvbuf[4][KS];
  __shared__ float wbs[4][64], wbq[4][64];
  int wv = threadIdx.x >> 6, lane = threadIdx.x & 63;
  int qid = blockIdx.x * 4 + wv;
  int b = qid >> 11;
  const float* pb = p + (size_t)b * NP * 3;
  float qx = newp[qid*3], qy = newp[qid*3+1], qz = newp[qid*3+2];
  float sq_q = __fadd_rn(__fadd_rn(__fmul_rn(qx,qx), __fmul_rn(qy,qy)), __fmul_rn(qz,qz));
  const float R2 = (float)(0.1 * 0.1);   // 0.009999999776482582f
  int found = 0, first = -1;
  float x = pb[lane*3], y = pb[lane*3+1], z = pb[lane*3+2];   // chunk 0
  for (int base = 0; base < NP; base += 64) {
    // prefetch next chunk (clamped when OOB; values then unused)
    int nf = (base + 64 < NP) ? (base + 64 + lane) : lane;
    float xn = pb[nf*3], yn = pb[nf*3+1], zn = pb[nf*3+2];
    int n = base + lane;
    float sq_p = __fadd_rn(__fadd_rn(__fmul_rn(x,x), __fmul_rn(y,y)), __fmul_rn(z,z));
    float dot  = __fadd_rn(__fadd_rn(__fmul_rn(qx,x), __fmul_rn(qy,y)), __fmul_rn(qz,z));
    float d2   = __fadd_rn(__fadd_rn(sq_q, sq_p), __fmul_rn(-2.0f, dot));
    bool hit = d2 < R2;
    unsigned long long mask = __ballot(hit);
    if (mask) {
      if (first < 0) first = base + __builtin_ctzll(mask);
      int cnt = __popcll(mask);
      if (found < KS) {
        int rank = __popcll(mask & ((1ull << lane) - 1ull));
        if (hit && found + rank < KS) nvbuf[wv][found + rank] = n;
      }
      found += cnt;
      if (found >= KS) break;
    }
    x = xn; y = yn; z = zn;
  }
  int fcl = found < KS ? found : KS;
  int padv = first < 0 ? 0 : first;
  if (lane >= fcl && lane < KS) nvbuf[wv][lane] = padv;
  // persist for p2 (coalesced 32-lane write); wave-internal LDS r/w
  if (lane < KS) nidx[(size_t)qid * KS + lane] = nvbuf[wv][lane];
  // ---- conv1 stats via g-gather: a = g[n][lane] - hq[lane] ----
  float w0 = w1[lane*67+0], w1c = w1[lane*67+1], w2c = w1[lane*67+2];
  float hq = w0*qx + w1c*qy + w2c*qz;
  float ss = 0.f, qq = 0.f;
  for (int kb = 0; kb < KS; kb += 8) {
    float gv[8];
    #pragma unroll
    for (int u = 0; u < 8; ++u) {
      int n = nvbuf[wv][kb + u];
      gv[u] = g[((size_t)b * NP + n) * 64 + lane];
    }
    #pragma unroll
    for (int u = 0; u < 8; ++u) {
      float a = gv[u] - hq;
      ss += a; qq += a * a;
    }
  }
  wbs[wv][lane] = ss; wbq[wv][lane] = qq;
  __syncthreads();
  if (threadIdx.x < 64) {
    float s  = wbs[0][threadIdx.x] + wbs[1][threadIdx.x] + wbs[2][threadIdx.x] + wbs[3][threadIdx.x];
    float s2 = wbq[0][threadIdx.x] + wbq[1][threadIdx.x] + wbq[2][threadIdx.x] + wbq[3][threadIdx.x];
    int slice = blockIdx.x & 63;
    atomicAdd(&stats1[(slice*2+0)*64 + threadIdx.x], s);
    atomicAdd(&stats1[(slice*2+1)*64 + threadIdx.x], s2);
  }
}

// ------------------------------------------------------------------
// P2 v4: fin1 INLINED (each thread reduces the 64 stat slices for
// its channel — same loop order/expressions as old fin1 -> same sc1
// up to contraction choice), then h = relu(bn1(g[n]-hq)) into LDS,
// conv2, stats2 + per-query max (bn2 commutes with max).
// ------------------------------------------------------------------
__global__ __launch_bounds__(256) void p2_kernel(
    const float* __restrict__ g, const float* __restrict__ newp,
    const float* __restrict__ w1, const float* __restrict__ w2,
    const int* __restrict__ nidx, const float* __restrict__ stats1,
    const float* __restrict__ g1, const float* __restrict__ b1,
    float* __restrict__ stats2, float* __restrict__ maxy2) {
  __shared__ __align__(16) float xbuf[4][KS][68];
  __shared__ float wbs[4][128], wbq[4][128];
  int wv = threadIdx.x >> 6, lane = threadIdx.x & 63;
  int qid = blockIdx.x * 4 + wv;
  int b = qid >> 11;
  // inline fin1 for channel = lane
  float s1v, t1v;
  {
    float s = 0.f, q = 0.f;
    for (int sl = 0; sl < 64; ++sl) {
      s += stats1[(sl*2+0)*64 + lane];
      q += stats1[(sl*2+1)*64 + lane];
    }
    const float cnt = (float)(BB * MQ * KS);
    float mean = s / cnt;
    float var = q / cnt - mean * mean;
    float rstd = 1.0f / sqrtf(var + 1e-5f);
    s1v = g1[lane] * rstd;
    t1v = b1[lane] - mean * s1v;
  }
  int nv = (lane < KS) ? nidx[(size_t)qid * KS + lane] : 0;
  float qx = newp[qid*3], qy = newp[qid*3+1], qz = newp[qid*3+2];
  float w0 = w1[lane*67+0], w1c = w1[lane*67+1], w2c = w1[lane*67+2];
  float hq = w0*qx + w1c*qy + w2c*qz;
  for (int kb = 0; kb < KS; kb += 8) {
    float gv[8];
    #pragma unroll
    for (int u = 0; u < 8; ++u) {
      int n = __shfl(nv, kb + u);
      gv[u] = g[((size_t)b * NP + n) * 64 + lane];
    }
    #pragma unroll
    for (int u = 0; u < 8; ++u) {
      float a = gv[u] - hq;
      float h = fmaxf(0.0f, fmaf(a, s1v, t1v));
      xbuf[wv][kb + u][lane] = h;
    }
  }
  __syncthreads();
  // conv2: lane computes channels lane and lane+64
  const float4* w2a = (const float4*)(w2 + (size_t)lane * 64);
  const float4* w2b = (const float4*)(w2 + (size_t)(lane + 64) * 64);
  float4 wra[16], wrb[16];
  #pragma unroll
  for (int c4 = 0; c4 < 16; ++c4) { wra[c4] = w2a[c4]; wrb[c4] = w2b[c4]; }
  float ss0 = 0.f, qq0 = 0.f, mx0 = -INFINITY;
  float ss1 = 0.f, qq1 = 0.f, mx1 = -INFINITY;
  for (int kk = 0; kk < KS; ++kk) {
    const float4* hr = (const float4*)(&xbuf[wv][kk][0]);
    float a0 = 0.f, a1 = 0.f;
    #pragma unroll
    for (int c4 = 0; c4 < 16; ++c4) {
      float4 h4 = hr[c4];
      float4 wa = wra[c4]; float4 wb = wrb[c4];
      a0 += wa.x*h4.x + wa.y*h4.y + wa.z*h4.z + wa.w*h4.w;
      a1 += wb.x*h4.x + wb.y*h4.y + wb.z*h4.z + wb.w*h4.w;
    }
    ss0 += a0; qq0 += a0*a0; mx0 = fmaxf(mx0, a0);
    ss1 += a1; qq1 += a1*a1; mx1 = fmaxf(mx1, a1);
  }
  maxy2[(size_t)qid * 128 + lane] = mx0;
  maxy2[(size_t)qid * 128 + 64 + lane] = mx1;
  wbs[wv][lane] = ss0; wbs[wv][64+lane] = ss1;
  wbq[wv][lane] = qq0; wbq[wv][64+lane] = qq1;
  __syncthreads();
  if (threadIdx.x < 128) {
    float s  = wbs[0][threadIdx.x] + wbs[1][threadIdx.x] + wbs[2][threadIdx.x] + wbs[3][threadIdx.x];
    float s2 = wbq[0][threadIdx.x] + wbq[1][threadIdx.x] + wbq[2][threadIdx.x] + wbq[3][threadIdx.x];
    int slice = blockIdx.x & 63;
    atomicAdd(&stats2[(slice*2+0)*128 + threadIdx.x], s);
    atomicAdd(&stats2[(slice*2+1)*128 + threadIdx.x], s2);
  }
}

// ------------------------------------------------------------------
// P3 v3: fin2 INLINED (per-thread reduction for channels lane and
// lane+64, same order/expressions as old fin2), skip conv from RAW f
// (column gather into LDS, broadcast float4 dot — identical
// arithmetic order), bn2 affine on max + relu.
// ------------------------------------------------------------------
__global__ __launch_bounds__(256) void p3_kernel(
    const float* __restrict__ f, const int* __restrict__ idx_i,
    const float* __restrict__ w_skip, const float* __restrict__ b_skip,
    const float* __restrict__ stats2,
    const float* __restrict__ g2, const float* __restrict__ b2,
    const float* __restrict__ maxy2, float* __restrict__ outf) {
  __shared__ __align__(16) float flds[4][64];
  int wv = threadIdx.x >> 6, lane = threadIdx.x & 63;
  int qid = blockIdx.x * 4 + wv;
  int b = qid >> 11, m = qid & (MQ - 1);
  int n = idx_i[qid];
  // inline fin2 for channels lane and lane+64
  float sc0, sh0, sc1v, sh1;
  {
    float s0 = 0.f, q0 = 0.f, s1 = 0.f, q1 = 0.f;
    for (int sl = 0; sl < 64; ++sl) {
      s0 += stats2[(sl*2+0)*128 + lane];
      q0 += stats2[(sl*2+1)*128 + lane];
      s1 += stats2[(sl*2+0)*128 + lane + 64];
      q1 += stats2[(sl*2+1)*128 + lane + 64];
    }
    const float cnt = (float)(BB * MQ * KS);
    float mean0 = s0 / cnt;
    float var0 = q0 / cnt - mean0 * mean0;
    float rstd0 = 1.0f / sqrtf(var0 + 1e-5f);
    sc0 = g2[lane] * rstd0;
    sh0 = b2[lane] - mean0 * sc0;
    float mean1 = s1 / cnt;
    float var1 = q1 / cnt - mean1 * mean1;
    float rstd1 = 1.0f / sqrtf(var1 + 1e-5f);
    sc1v = g2[lane + 64] * rstd1;
    sh1 = b2[lane + 64] - mean1 * sc1v;
  }
  flds[wv][lane] = f[((size_t)b * 64 + lane) * NP + n];   // column gather
  const float4* f4 = (const float4*)(&flds[wv][0]);        // same-wave w->r
  const float4* wa = (const float4*)(w_skip + (size_t)lane * 64);
  const float4* wb = (const float4*)(w_skip + (size_t)(lane + 64) * 64);
  float a0 = b_skip[lane], a1 = b_skip[lane + 64];
  #pragma unroll
  for (int c4 = 0; c4 < 16; ++c4) {
    float4 x = f4[c4]; float4 u = wa[c4]; float4 v = wb[c4];
    a0 += u.x*x.x + u.y*x.y + u.z*x.z + u.w*x.w;
    a1 += v.x*x.x + v.y*x.y + v.z*x.z + v.w*x.w;
  }
  float v0 = maxy2[(size_t)qid * 128 + lane];
  float v1 = maxy2[(size_t)qid * 128 + 64 + lane];
  float r0 = fmaxf(0.0f, fmaf(v0, sc0,  sh0) + a0);
  float r1 = fmaxf(0.0f, fmaf(v1, sc1v, sh1) + a1);
  outf[((size_t)b * 128 + lane) * MQ + m] = r0;
  outf[((size_t)b * 128 + lane + 64) * MQ + m] = r1;
}

// ------------------------------------------------------------------
extern "C" void kernel_launch(void* const* d_in, const int* in_sizes, int n_in,
                              void* d_out, int out_size, void* d_ws, size_t ws_size,
                              hipStream_t stream) {
  (void)in_sizes; (void)n_in; (void)out_size; (void)ws_size;
  const float* p   = (const float*)d_in[0];
  const float* f   = (const float*)d_in[1];
  const float* w1  = (const float*)d_in[2];
  const float* g1  = (const float*)d_in[3];
  const float* b1  = (const float*)d_in[4];
  const float* w2  = (const float*)d_in[5];
  const float* g2  = (const float*)d_in[6];
  const float* b2  = (const float*)d_in[7];
  const float* wsk = (const float*)d_in[8];
  const float* bsk = (const float*)d_in[9];
  float* out = (float*)d_out;
  float* wsf = (float*)d_ws;

  float* gbuf  = wsf + WS_G;
  int*   nidx  = (int*)(wsf + WS_NIDX);
  int*   idxi  = (int*)(wsf + WS_IDXI);
  float* st1   = wsf + WS_ST1;
  float* st2   = wsf + WS_ST2;
  float* maxy2 = wsf + WS_MAXY2;

  float* out_newp = out;
  float* out_f    = out + BB*MQ*3;

  // zero the atomic stats accumulators (st1+st2 are contiguous)
  (void)hipMemsetAsync(st1, 0, (8192 + 16384) * sizeof(float), stream);

  // fused: blocks 0..3 FPS, 4..515 g-precompute (in fps shadow)
  fps_fused_kernel<<<4 + 512, FPS_T, 0, stream>>>(p, out, idxi, f, gbuf, w1);
  bp1_kernel<<<BB*MQ/4, 256, 0, stream>>>(p, out_newp, gbuf, w1, nidx, st1);
  p2_kernel<<<BB*MQ/4, 256, 0, stream>>>(gbuf, out_newp, w1, w2, nidx, st1, g1, b1, st2, maxy2);
  p3_kernel<<<BB*MQ/4, 256, 0, stream>>>(f, idxi, wsk, bsk, st2, g2, b2, maxy2, out_f);
}

// Round 9
// 1913.882 us; speedup vs baseline: 1.0093x; 1.0093x over previous
//
#include <hip/hip_runtime.h>
#include <math.h>

#define BB 4
#define NP 8192
#define CF 64
#define MQ 2048
#define KS 32

// ---- workspace layout (float indices) ----
#define WS_G      0u         // g: [B][N][64] = W1_f·f_n + W1_dp·p_n (2097152 floats)
#define WS_NIDX   2097152u   // nidx: [B][M][K] int (262144)
#define WS_IDXI   2359296u   // idx int copy: [B][M] (8192)
#define WS_ST1    2367488u   // stats1 slices: [64][2][64] (8192)
#define WS_ST2    2375680u   // stats2 slices: [64][2][128] (16384)
#define WS_MAXY2  2392448u   // maxy2: [B*M][128] (1048576)

typedef float v2f __attribute__((ext_vector_type(2)));

// ------------------------------------------------------------------
// FPS v13 = r7 structure (best measured: 1897us total).
// r8 bundle (bp1 fusion + per-thread fin inline) regressed +35us ->
// unbundled: ballq/p1 stay separate (bp1 fusion regressed twice:
// r4 +66, r8). Kept from r8, in strictly-cheaper form: block-level
// fin inlining (wave0 reduces, LDS broadcast) and ballq prefetch.
// fps body frozen (~1630us; floor bracketed by 6 experiments:
// 256thr=1880cyc/iter < 512=2050 < 1024=2420; pk-asm/atomic/trim
// variants +-5%). Shadow blocks 4..515 compute g = W1_f·f_n +
// W1_dp·p_n (conv1 point-only part; conv1 = g[n] - W1_dp·q).
// ------------------------------------------------------------------
#define FPS_T 256
#define FPS_NK 16    // v2f pairs per thread: 32 points/thread

template <int CTRL>
__device__ __forceinline__ unsigned long long dpp_max_step(unsigned long long k) {
  int lo = (int)(unsigned)k;
  int hi = (int)(unsigned)(k >> 32);
  int slo = __builtin_amdgcn_update_dpp(0, lo, CTRL, 0xF, 0xF, true);
  int shi = __builtin_amdgcn_update_dpp(0, hi, CTRL, 0xF, 0xF, true);
  unsigned long long s =
      ((unsigned long long)(unsigned)shi << 32) | (unsigned long long)(unsigned)slo;
  return s > k ? s : k;
}

__global__ __launch_bounds__(256, 1) void fps_fused_kernel(
    const float* __restrict__ p, float* __restrict__ out, int* __restrict__ idx_i,
    const float* __restrict__ f, float* __restrict__ gout,
    const float* __restrict__ w1) {
#pragma clang fp contract(off)
  __shared__ __align__(16) char smem[NP * 16 + MQ * 4 + 2 * 4 * 8];
  int bx = blockIdx.x;
  int t = threadIdx.x;

  if (bx >= 4) {
    // ---- g block: tb in 0..511; b = tb>>7, n0 = (tb&127)*64 ----
    float (*tile)[65] = (float (*)[65])smem;                  // [64][65] f tile
    float (*wlds)[69] = (float (*)[69])(smem + 16640);        // [64][69] w1 rows (padded)
    float* plds = (float*)(smem + 16640 + 17664);             // [192] p coords
    int tb = bx - 4;
    int b = tb >> 7;
    int n0 = (tb & 127) * 64;
    int cc = t >> 6;   // 0..3
    int nn = t & 63;
    #pragma unroll
    for (int r = 0; r < 16; ++r) {
      int c = cc * 16 + r;
      tile[c][nn] = f[((size_t)b * 64 + c) * NP + n0 + nn];
    }
    for (int i = t; i < 64 * 67; i += 256) {
      wlds[i / 67][i % 67] = w1[i];
    }
    if (t < 192) plds[t] = p[((size_t)b * NP + n0) * 3 + t];
    __syncthreads();
    int wv = t >> 6, lane = t & 63;
    float wreg[67];
    #pragma unroll
    for (int c = 0; c < 67; ++c) wreg[c] = wlds[lane][c];
    for (int q = 0; q < 16; ++q) {
      int pt = wv * 16 + q;
      float acc = wreg[0] * plds[pt * 3 + 0];
      acc += wreg[1] * plds[pt * 3 + 1];
      acc += wreg[2] * plds[pt * 3 + 2];
      #pragma unroll
      for (int c = 0; c < 64; ++c) acc += wreg[3 + c] * tile[c][pt];
      gout[((size_t)b * NP + n0 + pt) * 64 + lane] = acc;
    }
    return;
  }

  // ---------------- FPS body (blocks 0..3, frozen) ----------------
  float4* sp4 = (float4*)smem;                                    // [NP]
  int* win = (int*)(smem + NP * 16);                              // [MQ]
  unsigned long long* wkey = (unsigned long long*)(smem + NP * 16 + MQ * 4); // [2][4]

  int b = bx;
  const float* pb = p + (size_t)b * NP * 3;
  float* out_newp = out;                               // [B][M][3]
  float* out_idxf = out + BB*MQ*3 + (size_t)BB*128*MQ; // [B][M] as float

  v2f px2[FPS_NK], py2[FPS_NK], pz2[FPS_NK];
  float dmn0[FPS_NK], dmn1[FPS_NK];          // even-slot / odd-slot dmin
  #pragma unroll
  for (int k = 0; k < FPS_NK; ++k) {
    int i0 = (2*k) * FPS_T + t;
    int i1 = i0 + FPS_T;
    float x0 = pb[i0*3+0], y0 = pb[i0*3+1], z0 = pb[i0*3+2];
    float x1 = pb[i1*3+0], y1 = pb[i1*3+1], z1 = pb[i1*3+2];
    px2[k] = (v2f){x0, x1}; py2[k] = (v2f){y0, y1}; pz2[k] = (v2f){z0, z1};
    sp4[i0] = make_float4(x0, y0, z0, 0.0f);
    sp4[i1] = make_float4(x1, y1, z1, 0.0f);
    dmn0[k] = INFINITY; dmn1[k] = INFINITY;
  }
  if (t == 0) win[0] = 0;
  __syncthreads();
  float lx = sp4[0].x, ly = sp4[0].y, lz = sp4[0].z;
  unsigned nt = ~(unsigned)t;

  for (int j = 1; j < MQ; ++j) {
#pragma clang fp contract(off)
    v2f l2x = (v2f){lx, lx}, l2y = (v2f){ly, ly}, l2z = (v2f){lz, lz};
    // dual strict-> argmax chains: chain0 = even slots (.x), chain1 = odd (.y)
    float bv0 = -1.0f, bv1 = -1.0f;
    unsigned bk0 = 0u, bk1 = 0u;
    #pragma unroll
    for (int k = 0; k < FPS_NK; ++k) {
      v2f dx = px2[k] - l2x;
      v2f dy = py2[k] - l2y;
      v2f dz = pz2[k] - l2z;
      v2f dd = ((dx*dx) + (dy*dy)) + (dz*dz);
      float m0 = fminf(dmn0[k], dd.x);  dmn0[k] = m0;
      float m1 = fminf(dmn1[k], dd.y);  dmn1[k] = m1;
      bool g0 = m0 > bv0;                 // strict > keeps earliest k
      bv0 = g0 ? m0 : bv0;
      bk0 = g0 ? (unsigned)k : bk0;
      bool g1 = m1 > bv1;
      bv1 = g1 ? m1 : bv1;
      bk1 = g1 ? (unsigned)k : bk1;
    }
    // ~((2*bk0)*256 + t) = nt - (bk0<<9); ~((2*bk1+1)*256 + t) = nt - (bk1<<9) - 256
    unsigned bn0 = nt - (bk0 << 9);
    unsigned bn1 = nt - (bk1 << 9) - 256u;
    unsigned long long k0 =
        ((unsigned long long)__float_as_uint(bv0) << 32) | (unsigned long long)bn0;
    unsigned long long k1 =
        ((unsigned long long)__float_as_uint(bv1) << 32) | (unsigned long long)bn1;
    unsigned long long key = k0 > k1 ? k0 : k1;   // ties: larger ~idx = smaller idx
    // DPP wave-max: result lands in lane 63
    key = dpp_max_step<0x111>(key);  // row_shr:1
    key = dpp_max_step<0x112>(key);  // row_shr:2
    key = dpp_max_step<0x114>(key);  // row_shr:4
    key = dpp_max_step<0x118>(key);  // row_shr:8
    key = dpp_max_step<0x142>(key);  // row_bcast15
    key = dpp_max_step<0x143>(key);  // row_bcast31
    if ((t & 63) == 63) wkey[(j & 1) * 4 + (t >> 6)] = key;   // 4 parallel slot writes
    __syncthreads();                 // single barrier per iteration
    const ulonglong2* wk2 = (const ulonglong2*)(&wkey[(j & 1) * 4]);
    ulonglong2 ka = wk2[0];          // broadcast ds_read_b128
    ulonglong2 kb = wk2[1];
    unsigned long long m0 = ka.x > ka.y ? ka.x : ka.y;
    unsigned long long m1 = kb.x > kb.y ? kb.x : kb.y;
    unsigned long long kw = m0 > m1 ? m0 : m1;
    int wi = (int)(~(unsigned)kw);
    float4 c = sp4[wi];              // one ds_read_b128, same-addr broadcast
    lx = c.x; ly = c.y; lz = c.z;
    if (t == 0) win[j] = wi;
  }

  __syncthreads();
  // bulk coalesced epilogue: idx (float + int) and new_p from LDS
  #pragma unroll
  for (int k = 0; k < MQ / FPS_T; ++k) {
    int j = k * FPS_T + t;
    int wi = win[j];
    out_idxf[b*MQ + j] = (float)wi;
    idx_i[b*MQ + j] = wi;
    float4 c = sp4[wi];
    float* np_ = &out_newp[(size_t)(b*MQ + j) * 3];
    np_[0] = c.x; np_[1] = c.y; np_[2] = c.z;
  }
}

// ------------------------------------------------------------------
// ball query (standalone, high-occupancy): one wave per query.
// rn ops; R2 = f32(0.1*0.1); pad first-hit/0. Software-pipelined:
// next chunk's 3 loads issue before the current ballot/branch (same
// values, same chunk order; OOB prefetch clamped, values unused).
// ------------------------------------------------------------------
__global__ __launch_bounds__(256) void ballq_kernel(
    const float* __restrict__ p, const float* __restrict__ newp,
    int* __restrict__ nidx) {
  int qid = blockIdx.x * 4 + (threadIdx.x >> 6);   // b*M+m
  int lane = threadIdx.x & 63;
  int b = qid >> 11;
  const float* pb = p + (size_t)b * NP * 3;
  float qx = newp[qid*3], qy = newp[qid*3+1], qz = newp[qid*3+2];
  float sq_q = __fadd_rn(__fadd_rn(__fmul_rn(qx,qx), __fmul_rn(qy,qy)), __fmul_rn(qz,qz));
  const float R2 = (float)(0.1 * 0.1);   // 0.009999999776482582f
  int found = 0, first = -1;
  int* outp = nidx + (size_t)qid * KS;
  float x = pb[lane*3], y = pb[lane*3+1], z = pb[lane*3+2];   // chunk 0
  for (int base = 0; base < NP; base += 64) {
    int nf = (base + 64 < NP) ? (base + 64 + lane) : lane;    // prefetch next
    float xn = pb[nf*3], yn = pb[nf*3+1], zn = pb[nf*3+2];
    int n = base + lane;
    float sq_p = __fadd_rn(__fadd_rn(__fmul_rn(x,x), __fmul_rn(y,y)), __fmul_rn(z,z));
    float dot  = __fadd_rn(__fadd_rn(__fmul_rn(qx,x), __fmul_rn(qy,y)), __fmul_rn(qz,z));
    float d2   = __fadd_rn(__fadd_rn(sq_q, sq_p), __fmul_rn(-2.0f, dot));
    bool hit = d2 < R2;
    unsigned long long mask = __ballot(hit);
    if (mask) {
      if (first < 0) first = base + __builtin_ctzll(mask);
      int cnt = __popcll(mask);
      if (found < KS) {
        int rank = __popcll(mask & ((1ull << lane) - 1ull));
        if (hit && found + rank < KS) outp[found + rank] = n;
      }
      found += cnt;
      if (found >= KS) break;
    }
    x = xn; y = yn; z = zn;
  }
  int fcl = found < KS ? found : KS;
  int padv = first < 0 ? 0 : first;
  if (lane >= fcl && lane < KS) outp[lane] = padv;
}

// ------------------------------------------------------------------
// P1: conv1 stats via g-gather. a = g[n][lane] - hq[lane],
// hq = W1_dp·q. 8-deep staged coalesced row loads. (r7 version.)
// ------------------------------------------------------------------
__global__ __launch_bounds__(256) void p1_kernel(
    const float* __restrict__ g, const float* __restrict__ newp,
    const float* __restrict__ w1, const int* __restrict__ nidx,
    float* __restrict__ stats1) {
  __shared__ float wbs[4][64], wbq[4][64];
  int wv = threadIdx.x >> 6, lane = threadIdx.x & 63;
  int qid = blockIdx.x * 4 + wv;
  int b = qid >> 11;
  int nv = (lane < KS) ? nidx[(size_t)qid * KS + lane] : 0;
  float qx = newp[qid*3], qy = newp[qid*3+1], qz = newp[qid*3+2];
  float w0 = w1[lane*67+0], w1c = w1[lane*67+1], w2c = w1[lane*67+2];
  float hq = w0*qx + w1c*qy + w2c*qz;
  float ss = 0.f, qq = 0.f;
  for (int kb = 0; kb < KS; kb += 8) {
    float gv[8];
    #pragma unroll
    for (int u = 0; u < 8; ++u) {
      int n = __shfl(nv, kb + u);
      gv[u] = g[((size_t)b * NP + n) * 64 + lane];
    }
    #pragma unroll
    for (int u = 0; u < 8; ++u) {
      float a = gv[u] - hq;
      ss += a; qq += a * a;
    }
  }
  wbs[wv][lane] = ss; wbq[wv][lane] = qq;
  __syncthreads();
  if (threadIdx.x < 64) {
    float s  = wbs[0][threadIdx.x] + wbs[1][threadIdx.x] + wbs[2][threadIdx.x] + wbs[3][threadIdx.x];
    float s2 = wbq[0][threadIdx.x] + wbq[1][threadIdx.x] + wbq[2][threadIdx.x] + wbq[3][threadIdx.x];
    int slice = blockIdx.x & 63;
    atomicAdd(&stats1[(slice*2+0)*64 + threadIdx.x], s);
    atomicAdd(&stats1[(slice*2+1)*64 + threadIdx.x], s2);
  }
}

// ------------------------------------------------------------------
// P2 v5: fin1 inlined BLOCK-LEVEL (threads 0..63 reduce the 64
// slices for channel tid — same loop order/expressions as old fin1
// -> bit-identical sc1 — into LDS; one barrier; all read). Then
// h = relu(bn1(g[n]-hq)) into LDS, conv2, stats2 + per-query max.
// ------------------------------------------------------------------
__global__ __launch_bounds__(256) void p2_kernel(
    const float* __restrict__ g, const float* __restrict__ newp,
    const float* __restrict__ w1, const float* __restrict__ w2,
    const int* __restrict__ nidx, const float* __restrict__ stats1,
    const float* __restrict__ g1, const float* __restrict__ b1,
    float* __restrict__ stats2, float* __restrict__ maxy2) {
  __shared__ __align__(16) float xbuf[4][KS][68];
  __shared__ float wbs[4][128], wbq[4][128];
  __shared__ float scb[128];   // s1v[64] | t1v[64]
  int wv = threadIdx.x >> 6, lane = threadIdx.x & 63;
  int qid = blockIdx.x * 4 + wv;
  int b = qid >> 11;
  if (threadIdx.x < 64) {
    int o = threadIdx.x;
    float s = 0.f, q = 0.f;
    for (int sl = 0; sl < 64; ++sl) {
      s += stats1[(sl*2+0)*64 + o];
      q += stats1[(sl*2+1)*64 + o];
    }
    const float cnt = (float)(BB * MQ * KS);
    float mean = s / cnt;
    float var = q / cnt - mean * mean;
    float rstd = 1.0f / sqrtf(var + 1e-5f);
    float gs = g1[o] * rstd;
    scb[o] = gs;
    scb[64 + o] = b1[o] - mean * gs;
  }
  int nv = (lane < KS) ? nidx[(size_t)qid * KS + lane] : 0;
  float qx = newp[qid*3], qy = newp[qid*3+1], qz = newp[qid*3+2];
  float w0 = w1[lane*67+0], w1c = w1[lane*67+1], w2c = w1[lane*67+2];
  float hq = w0*qx + w1c*qy + w2c*qz;
  __syncthreads();
  float s1v = scb[lane], t1v = scb[64 + lane];
  for (int kb = 0; kb < KS; kb += 8) {
    float gv[8];
    #pragma unroll
    for (int u = 0; u < 8; ++u) {
      int n = __shfl(nv, kb + u);
      gv[u] = g[((size_t)b * NP + n) * 64 + lane];
    }
    #pragma unroll
    for (int u = 0; u < 8; ++u) {
      float a = gv[u] - hq;
      float h = fmaxf(0.0f, fmaf(a, s1v, t1v));
      xbuf[wv][kb + u][lane] = h;
    }
  }
  __syncthreads();
  // conv2: lane computes channels lane and lane+64
  const float4* w2a = (const float4*)(w2 + (size_t)lane * 64);
  const float4* w2b = (const float4*)(w2 + (size_t)(lane + 64) * 64);
  float4 wra[16], wrb[16];
  #pragma unroll
  for (int c4 = 0; c4 < 16; ++c4) { wra[c4] = w2a[c4]; wrb[c4] = w2b[c4]; }
  float ss0 = 0.f, qq0 = 0.f, mx0 = -INFINITY;
  float ss1 = 0.f, qq1 = 0.f, mx1 = -INFINITY;
  for (int kk = 0; kk < KS; ++kk) {
    const float4* hr = (const float4*)(&xbuf[wv][kk][0]);
    float a0 = 0.f, a1 = 0.f;
    #pragma unroll
    for (int c4 = 0; c4 < 16; ++c4) {
      float4 h4 = hr[c4];
      float4 wa = wra[c4]; float4 wb = wrb[c4];
      a0 += wa.x*h4.x + wa.y*h4.y + wa.z*h4.z + wa.w*h4.w;
      a1 += wb.x*h4.x + wb.y*h4.y + wb.z*h4.z + wb.w*h4.w;
    }
    ss0 += a0; qq0 += a0*a0; mx0 = fmaxf(mx0, a0);
    ss1 += a1; qq1 += a1*a1; mx1 = fmaxf(mx1, a1);
  }
  maxy2[(size_t)qid * 128 + lane] = mx0;
  maxy2[(size_t)qid * 128 + 64 + lane] = mx1;
  wbs[wv][lane] = ss0; wbs[wv][64+lane] = ss1;
  wbq[wv][lane] = qq0; wbq[wv][64+lane] = qq1;
  __syncthreads();
  if (threadIdx.x < 128) {
    float s  = wbs[0][threadIdx.x] + wbs[1][threadIdx.x] + wbs[2][threadIdx.x] + wbs[3][threadIdx.x];
    float s2 = wbq[0][threadIdx.x] + wbq[1][threadIdx.x] + wbq[2][threadIdx.x] + wbq[3][threadIdx.x];
    int slice = blockIdx.x & 63;
    atomicAdd(&stats2[(slice*2+0)*128 + threadIdx.x], s);
    atomicAdd(&stats2[(slice*2+1)*128 + threadIdx.x], s2);
  }
}

// ------------------------------------------------------------------
// P3 v4: fin2 inlined BLOCK-LEVEL (threads 0..127 reduce channel
// tid — same order/expressions as old fin2 -> bit-identical sc2 —
// into LDS), skip conv from RAW f (column gather, broadcast float4
// dot — identical arithmetic order), bn2 affine on max + relu.
// ------------------------------------------------------------------
__global__ __launch_bounds__(256) void p3_kernel(
    const float* __restrict__ f, const int* __restrict__ idx_i,
    const float* __restrict__ w_skip, const float* __restrict__ b_skip,
    const float* __restrict__ stats2,
    const float* __restrict__ g2, const float* __restrict__ b2,
    const float* __restrict__ maxy2, float* __restrict__ outf) {
  __shared__ __align__(16) float flds[4][64];
  __shared__ float scb[256];   // sc[128] | sh[128]
  int wv = threadIdx.x >> 6, lane = threadIdx.x & 63;
  int qid = blockIdx.x * 4 + wv;
  int b = qid >> 11, m = qid & (MQ - 1);
  int n = idx_i[qid];
  if (threadIdx.x < 128) {
    int o = threadIdx.x;
    float s = 0.f, q = 0.f;
    for (int sl = 0; sl < 64; ++sl) {
      s += stats2[(sl*2+0)*128 + o];
      q += stats2[(sl*2+1)*128 + o];
    }
    const float cnt = (float)(BB * MQ * KS);
    float mean = s / cnt;
    float var = q / cnt - mean * mean;
    float rstd = 1.0f / sqrtf(var + 1e-5f);
    float gs = g2[o] * rstd;
    scb[o] = gs;
    scb[128 + o] = b2[o] - mean * gs;
  }
  flds[wv][lane] = f[((size_t)b * 64 + lane) * NP + n];   // column gather
  __syncthreads();
  const float4* f4 = (const float4*)(&flds[wv][0]);
  const float4* wa = (const float4*)(w_skip + (size_t)lane * 64);
  const float4* wb = (const float4*)(w_skip + (size_t)(lane + 64) * 64);
  float a0 = b_skip[lane], a1 = b_skip[lane + 64];
  #pragma unroll
  for (int c4 = 0; c4 < 16; ++c4) {
    float4 x = f4[c4]; float4 u = wa[c4]; float4 v = wb[c4];
    a0 += u.x*x.x + u.y*x.y + u.z*x.z + u.w*x.w;
    a1 += v.x*x.x + v.y*x.y + v.z*x.z + v.w*x.w;
  }
  float v0 = maxy2[(size_t)qid * 128 + lane];
  float v1 = maxy2[(size_t)qid * 128 + 64 + lane];
  float r0 = fmaxf(0.0f, fmaf(v0, scb[lane],      scb[128 + lane])      + a0);
  float r1 = fmaxf(0.0f, fmaf(v1, scb[lane + 64], scb[128 + lane + 64]) + a1);
  outf[((size_t)b * 128 + lane) * MQ + m] = r0;
  outf[((size_t)b * 128 + lane + 64) * MQ + m] = r1;
}

// ------------------------------------------------------------------
extern "C" void kernel_launch(void* const* d_in, const int* in_sizes, int n_in,
                              void* d_out, int out_size, void* d_ws, size_t ws_size,
                              hipStream_t stream) {
  (void)in_sizes; (void)n_in; (void)out_size; (void)ws_size;
  const float* p   = (const float*)d_in[0];
  const float* f   = (const float*)d_in[1];
  const float* w1  = (const float*)d_in[2];
  const float* g1  = (const float*)d_in[3];
  const float* b1  = (const float*)d_in[4];
  const float* w2  = (const float*)d_in[5];
  const float* g2  = (const float*)d_in[6];
  const float* b2  = (const float*)d_in[7];
  const float* wsk = (const float*)d_in[8];
  const float* bsk = (const float*)d_in[9];
  float* out = (float*)d_out;
  float* wsf = (float*)d_ws;

  float* gbuf  = wsf + WS_G;
  int*   nidx  = (int*)(wsf + WS_NIDX);
  int*   idxi  = (int*)(wsf + WS_IDXI);
  float* st1   = wsf + WS_ST1;
  float* st2   = wsf + WS_ST2;
  float* maxy2 = wsf + WS_MAXY2;

  float* out_newp = out;
  float* out_f    = out + BB*MQ*3;

  // zero the atomic stats accumulators (st1+st2 are contiguous)
  (void)hipMemsetAsync(st1, 0, (8192 + 16384) * sizeof(float), stream);

  // fused: blocks 0..3 FPS, 4..515 g-precompute (in fps shadow)
  fps_fused_kernel<<<4 + 512, FPS_T, 0, stream>>>(p, out, idxi, f, gbuf, w1);
  ballq_kernel<<<BB*MQ/4, 256, 0, stream>>>(p, out_newp, nidx);
  p1_kernel<<<BB*MQ/4, 256, 0, stream>>>(gbuf, out_newp, w1, nidx, st1);
  p2_kernel<<<BB*MQ/4, 256, 0, stream>>>(gbuf, out_newp, w1, w2, nidx, st1, g1, b1, st2, maxy2);
  p3_kernel<<<BB*MQ/4, 256, 0, stream>>>(f, idxi, wsk, bsk, st2, g2, b2, maxy2, out_f);
}